// Round 1
// baseline (335.005 us; speedup 1.0000x reference)
//
#include <hip/hip_runtime.h>
#include <hip/hip_bf16.h>
#include <math.h>

#define N_FRAMES 100000
#define HIDDEN 512
#define N_QUERIES 256
#define N_EVENTS 2048
#define TOPK 8
#define FRAME_RATE 5.0f
#define EPSN 1e-12f

// ---------------- ws layout (bytes) ----------------
// avg     : [2048][512] f32   @ 0          (4 MB)
// ts      : [2048][2]   f32   @ 4194304
// inv_en  : [2048]      f32   @ 4210688
// inv_qn  : [256]       f32   @ 4218880
// start   : [2048]      i32   @ 4219904
// end     : [2048]      i32   @ 4228096
// sim     : [256][2048] f32   @ 4236288    (2 MB)
// top_idx : [256][8]    i32   @ 6333440
// total ~6.34 MB

__global__ void init_k(int* __restrict__ start, int* __restrict__ end) {
    int e = blockIdx.x * blockDim.x + threadIdx.x;
    if (e < N_EVENTS) { start[e] = -1; end[e] = -1; }
}

__global__ void bounds_k(const int* __restrict__ ev, int* __restrict__ start,
                         int* __restrict__ end) {
    int i = blockIdx.x * blockDim.x + threadIdx.x;
    if (i >= N_FRAMES) return;
    int e = ev[i];
    if (i == 0 || ev[i - 1] != e) start[e] = i;
    if (i == N_FRAMES - 1 || ev[i + 1] != e) end[e] = i;
}

// one block (256 threads) per event; threads 0..127 & 128..255 take alternating frames
__global__ void pool_k(const float* __restrict__ vf, const int* __restrict__ start,
                       const int* __restrict__ end, float* __restrict__ avg,
                       float* __restrict__ inv_en, float* __restrict__ ts) {
    int e = blockIdx.x;
    int s = start[e], t = end[e];
    int tid = threadIdx.x;
    int half = tid >> 7;      // 0 or 1
    int l = tid & 127;        // float4 column within the 512-f32 row
    float4 acc = make_float4(0.f, 0.f, 0.f, 0.f);
    if (s >= 0) {
        const float4* p = (const float4*)vf + (size_t)(s + half) * 128 + l;
        int f = s + half;
        // unrolled-by-2 over this thread's frames (stride 2 frames)
        for (; f + 2 <= t; f += 4, p += 512) {
            float4 v0 = p[0];
            float4 v1 = p[256];
            acc.x += v0.x + v1.x; acc.y += v0.y + v1.y;
            acc.z += v0.z + v1.z; acc.w += v0.w + v1.w;
        }
        if (f <= t) {
            float4 v0 = *p;
            acc.x += v0.x; acc.y += v0.y; acc.z += v0.z; acc.w += v0.w;
        }
    }
    __shared__ float4 buf[128];
    __shared__ float ssbuf[2];
    if (half) buf[l] = acc;
    __syncthreads();
    if (!half) {
        float4 o = buf[l];
        acc.x += o.x; acc.y += o.y; acc.z += o.z; acc.w += o.w;
        if (s >= 0) {
            float cnt = (float)(t - s + 1);
            acc.x = acc.x / cnt; acc.y = acc.y / cnt;
            acc.z = acc.z / cnt; acc.w = acc.w / cnt;
        }
        *((float4*)avg + (size_t)e * 128 + l) = acc;
        float ss = acc.x * acc.x + acc.y * acc.y + acc.z * acc.z + acc.w * acc.w;
        #pragma unroll
        for (int off = 32; off; off >>= 1) ss += __shfl_xor(ss, off);
        if ((tid & 63) == 0) ssbuf[tid >> 6] = ss;
    }
    __syncthreads();
    if (tid == 0) {
        float ss = ssbuf[0] + ssbuf[1];
        inv_en[e] = (s >= 0) ? 1.0f / fmaxf(sqrtf(ss), EPSN) : 0.0f;
        ts[e * 2 + 0] = (s >= 0) ? (float)s / FRAME_RATE : 0.0f;
        ts[e * 2 + 1] = (s >= 0) ? (float)t / FRAME_RATE : 0.0f;
    }
}

__global__ void qnorm_k(const float* __restrict__ qf, float* __restrict__ inv_qn) {
    int q = blockIdx.x;
    int lane = threadIdx.x;  // 64
    const float* row = qf + (size_t)q * HIDDEN;
    float ss = 0.f;
    #pragma unroll
    for (int i = 0; i < 8; ++i) { float v = row[lane + 64 * i]; ss += v * v; }
    #pragma unroll
    for (int off = 32; off; off >>= 1) ss += __shfl_xor(ss, off);
    if (lane == 0) inv_qn[q] = 1.0f / fmaxf(sqrtf(ss), EPSN);
}

// sim tile: BQ=64 queries x BE=32 events per block; 256 threads, micro-tile 4q x 2e.
#define BQ 64
#define BE 32
#define DC 128
#define DCP 132   // +4 pad keeps float4 alignment, breaks bank aliasing

__global__ void sim_k(const float* __restrict__ qf, const float* __restrict__ avg,
                      const float* __restrict__ inv_qn, const float* __restrict__ inv_en,
                      float* __restrict__ sim) {
    __shared__ float qs[BQ][DCP];
    __shared__ float es[BE][DCP];
    int tid = threadIdx.x;
    int qbase = blockIdx.y * BQ;
    int ebase = blockIdx.x * BE;
    int e0 = tid & 15;   // events e0, e0+16
    int q0 = tid >> 4;   // queries q0 + 16*i
    float acc[4][2] = {{0.f, 0.f}, {0.f, 0.f}, {0.f, 0.f}, {0.f, 0.f}};
    for (int dc = 0; dc < HIDDEN; dc += DC) {
        __syncthreads();
        #pragma unroll
        for (int r = 0; r < 8; ++r) {     // 64x128 f32 = 2048 float4 / 256 thr
            int ldx = tid + 256 * r;
            int row = ldx >> 5, c4 = ldx & 31;
            float4 v = *(const float4*)(qf + (size_t)(qbase + row) * HIDDEN + dc + c4 * 4);
            *(float4*)&qs[row][c4 * 4] = v;
        }
        #pragma unroll
        for (int r = 0; r < 4; ++r) {     // 32x128 f32 = 1024 float4 / 256 thr
            int ldx = tid + 256 * r;
            int row = ldx >> 5, c4 = ldx & 31;
            float4 v = *(const float4*)(avg + (size_t)(ebase + row) * HIDDEN + dc + c4 * 4);
            *(float4*)&es[row][c4 * 4] = v;
        }
        __syncthreads();
        #pragma unroll 4
        for (int d = 0; d < DC; d += 4) {
            float4 ev0 = *(const float4*)&es[e0][d];
            float4 ev1 = *(const float4*)&es[e0 + 16][d];
            #pragma unroll
            for (int i = 0; i < 4; ++i) {
                float4 qv = *(const float4*)&qs[q0 + 16 * i][d];
                acc[i][0] += qv.x * ev0.x + qv.y * ev0.y + qv.z * ev0.z + qv.w * ev0.w;
                acc[i][1] += qv.x * ev1.x + qv.y * ev1.y + qv.z * ev1.z + qv.w * ev1.w;
            }
        }
    }
    float iq[4];
    #pragma unroll
    for (int i = 0; i < 4; ++i) iq[i] = inv_qn[qbase + q0 + 16 * i];
    float ie0 = inv_en[ebase + e0];
    float ie1 = inv_en[ebase + e0 + 16];
    #pragma unroll
    for (int i = 0; i < 4; ++i) {
        size_t rowoff = (size_t)(qbase + q0 + 16 * i) * N_EVENTS + ebase;
        sim[rowoff + e0] = acc[i][0] * iq[i] * ie0;
        sim[rowoff + e0 + 16] = acc[i][1] * iq[i] * ie1;
    }
}

// one wave per query; top-8 with lower-index tie-break (matches jax.lax.top_k)
__global__ void topk_k(const float* __restrict__ sim, int* __restrict__ top_idx) {
    int q = blockIdx.x;
    int lane = threadIdx.x;  // 64
    const float* row = sim + (size_t)q * N_EVENTS;
    float v[32];
    #pragma unroll
    for (int i = 0; i < 32; ++i) v[i] = row[lane + 64 * i];
    int chosen[TOPK];
    #pragma unroll
    for (int k = 0; k < TOPK; ++k) {
        float best = -INFINITY;
        int bidx = 0x7fffffff;
        #pragma unroll
        for (int i = 0; i < 32; ++i) {
            int idx = lane + 64 * i;
            bool dup = false;
            #pragma unroll
            for (int j = 0; j < TOPK; ++j) dup = dup || ((j < k) && (chosen[j] == idx));
            if (!dup && v[i] > best) { best = v[i]; bidx = idx; }
        }
        #pragma unroll
        for (int off = 32; off; off >>= 1) {
            float ov = __shfl_xor(best, off);
            int oi = __shfl_xor(bidx, off);
            if (ov > best || (ov == best && oi < bidx)) { best = ov; bidx = oi; }
        }
        chosen[k] = bidx;   // k is compile-time (loop unrolled) -> stays in regs
        if (lane == 0) top_idx[q * TOPK + k] = bidx;
    }
}

// one wave per (q,k) pair
__global__ void final_k(const float* __restrict__ avg, const float* __restrict__ qf,
                        const float* __restrict__ ts, const int* __restrict__ top_idx,
                        const float* __restrict__ W, const float* __restrict__ b,
                        float* __restrict__ out) {
    int blk = blockIdx.x;          // q*8 + k
    int q = blk >> 3;
    int lane = threadIdx.x;        // 64
    int e = top_idx[blk];
    const float* frow = avg + (size_t)e * HIDDEN;
    const float* qrow = qf + (size_t)q * HIDDEN;
    float a0 = 0.f, a1 = 0.f;
    #pragma unroll
    for (int i = 0; i < 8; ++i) {
        int d = lane + 64 * i;
        float f = frow[d] * qrow[d];
        a0 += f * W[d * 2 + 0];
        a1 += f * W[d * 2 + 1];
    }
    #pragma unroll
    for (int off = 32; off; off >>= 1) {
        a0 += __shfl_xor(a0, off);
        a1 += __shfl_xor(a1, off);
    }
    if (lane == 0) {
        float b0 = tanhf(a0 + b[0]);
        float b1 = tanhf(a1 + b[1]);
        float t0 = ts[e * 2 + 0], t1 = ts[e * 2 + 1];
        float dur = t1 - t0;
        out[blk * 2 + 0] = t0 + b0 * dur;
        out[blk * 2 + 1] = t1 + b1 * dur;
    }
}

extern "C" void kernel_launch(void* const* d_in, const int* in_sizes, int n_in,
                              void* d_out, int out_size, void* d_ws, size_t ws_size,
                              hipStream_t stream) {
    const float* vf = (const float*)d_in[0];      // [1,100000,512]
    const float* qf = (const float*)d_in[1];      // [256,512]
    const int* ev = (const int*)d_in[2];          // [100000]
    const float* W = (const float*)d_in[3];       // [512,2]
    const float* b = (const float*)d_in[4];       // [2]
    float* out = (float*)d_out;

    char* ws = (char*)d_ws;
    float* avg    = (float*)(ws + 0);
    float* ts     = (float*)(ws + 4194304);
    float* inv_en = (float*)(ws + 4210688);
    float* inv_qn = (float*)(ws + 4218880);
    int*   start  = (int*)  (ws + 4219904);
    int*   endp   = (int*)  (ws + 4228096);
    float* sim    = (float*)(ws + 4236288);
    int*   tidx   = (int*)  (ws + 6333440);

    init_k<<<(N_EVENTS + 255) / 256, 256, 0, stream>>>(start, endp);
    bounds_k<<<(N_FRAMES + 255) / 256, 256, 0, stream>>>(ev, start, endp);
    pool_k<<<N_EVENTS, 256, 0, stream>>>(vf, start, endp, avg, inv_en, ts);
    qnorm_k<<<N_QUERIES, 64, 0, stream>>>(qf, inv_qn);
    dim3 sgrid(N_EVENTS / BE, N_QUERIES / BQ);
    sim_k<<<sgrid, 256, 0, stream>>>(qf, avg, inv_qn, inv_en, sim);
    topk_k<<<N_QUERIES, 64, 0, stream>>>(sim, tidx);
    final_k<<<N_QUERIES * TOPK, 64, 0, stream>>>(avg, qf, ts, tidx, W, b, out);
}